// Round 2
// baseline (1067.483 us; speedup 1.0000x reference)
//
#include <hip/hip_runtime.h>
#include <hip/hip_bf16.h>

#define BATCH 2
#define NPB   2048
#define NPTS  4096   // BATCH*NPB
#define KNB   27
#define FCATC 1440

typedef __hip_bfloat16 bf16;

__device__ __forceinline__ float b2f(bf16 v) { return __bfloat162float(v); }

// load input element i from buffer p whose dtype is fp32 (f32=1) or bf16 (f32=0)
__device__ __forceinline__ float ldin(const void* p, size_t i, int f32) {
    return f32 ? ((const float*)p)[i] : b2f(((const bf16*)p)[i]);
}

// ---------------- dtype detect: bf16-interpret x; any huge/NaN => underlying fp32 ----------------
__global__ void k_detect(const void* __restrict__ x, int* __restrict__ flag) {
    __shared__ int s;
    if (threadIdx.x == 0) s = 0;
    __syncthreads();
    const bf16* xb = (const bf16*)x;
    int local = 0;
    for (int i = threadIdx.x; i < NPTS * 3; i += 256) {
        float v = b2f(xb[i]);
        if (!(fabsf(v) < 1e4f)) local = 1;   // catches NaN/Inf/huge
    }
    if (local) s = 1;
    __syncthreads();
    if (threadIdx.x == 0) flag[0] = s;       // 1 => fp32 underlying
}

// ---------------- convert x to fp32 ----------------
__global__ void k_convx(const void* __restrict__ x, const int* __restrict__ flag, float* __restrict__ xf) {
    int i = blockIdx.x * 256 + threadIdx.x;
    if (i >= NPTS * 3) return;
    xf[i] = ldin(x, i, flag[0]);
}

// ---------------- zero accumulators ----------------
__global__ void k_zero(float* p, int n) {
    int i = blockIdx.x * 256 + threadIdx.x;
    if (i < n) p[i] = 0.f;
}

// ---------------- KNN: top-27 by max of negative sq dist ----------------
__global__ __launch_bounds__(256) void k_knn(const float* __restrict__ x, int* __restrict__ idx) {
    __shared__ float ds[NPB];
    __shared__ float rv[4];
    __shared__ int   ri[4];
    int bn = blockIdx.x;            // 0..4095
    int b = bn >> 11, n = bn & (NPB - 1);
    const float* xb = x + (size_t)b * NPB * 3;
    float cx = xb[n * 3 + 0];
    float cy = xb[n * 3 + 1];
    float cz = xb[n * 3 + 2];
    float cc = cx * cx + cy * cy + cz * cz;
    for (int m = threadIdx.x; m < NPB; m += 256) {
        float mx = xb[m * 3 + 0];
        float my = xb[m * 3 + 1];
        float mz = xb[m * 3 + 2];
        float mm = mx * mx + my * my + mz * mz;
        float dot = cx * mx + cy * my + cz * mz;
        ds[m] = 2.f * dot - cc - mm;
    }
    __syncthreads();
    int lane = threadIdx.x & 63, wv = threadIdx.x >> 6;
    for (int kk = 0; kk < KNB; kk++) {
        float bv = -INFINITY; int bi = 0x7fffffff;
        for (int m = threadIdx.x; m < NPB; m += 256) {
            float v = ds[m];
            if (v > bv || (v == bv && m < bi)) { bv = v; bi = m; }
        }
        for (int off = 32; off > 0; off >>= 1) {
            float ov = __shfl_down(bv, off);
            int   oi = __shfl_down(bi, off);
            if (ov > bv || (ov == bv && oi < bi)) { bv = ov; bi = oi; }
        }
        if (lane == 0) { rv[wv] = bv; ri[wv] = bi; }
        __syncthreads();
        if (threadIdx.x == 0) {
            float fv = rv[0]; int fi = ri[0];
            for (int w = 1; w < 4; w++)
                if (rv[w] > fv || (rv[w] == fv && ri[w] < fi)) { fv = rv[w]; fi = ri[w]; }
            if (fi < 0 || fi >= NPB) fi = 0;     // safety: never OOB
            idx[bn * KNB + kk] = b * NPB + fi;   // global point id
            ds[fi] = -INFINITY;
        }
        __syncthreads();
    }
}

// ---------------- W transpose + u/v transform ----------------
// Wt[c*N2 + o] : o<Co -> W[o, c] (left);  o>=Co -> W[o-Co, Cin+c] - W[o-Co, c]
__global__ void k_wt_edge(const void* __restrict__ W, const int* __restrict__ flag,
                          float* __restrict__ Wt, int Cin, int Co) {
    int o = blockIdx.x * 256 + threadIdx.x;
    int N2 = 2 * Co;
    if (o >= N2) return;
    int f32 = flag[0];
    int c0 = blockIdx.y * 32;
    int c1 = c0 + 32; if (c1 > Cin) c1 = Cin;
    if (o < Co) {
        for (int c = c0; c < c1; c++)
            Wt[(size_t)c * N2 + o] = ldin(W, (size_t)o * 2 * Cin + c, f32);
    } else {
        int oo = o - Co;
        for (int c = c0; c < c1; c++)
            Wt[(size_t)c * N2 + o] = ldin(W, (size_t)oo * 2 * Cin + Cin + c, f32)
                                   - ldin(W, (size_t)oo * 2 * Cin + c, f32);
    }
}

__global__ void k_wt_final(const void* __restrict__ W4, const int* __restrict__ flag, float* __restrict__ Wt) {
    int o = threadIdx.x;                 // 0..255
    int f32 = flag[0];
    int c0 = blockIdx.y * 32;
    int c1 = c0 + 32; if (c1 > FCATC) c1 = FCATC;
    for (int c = c0; c < c1; c++)
        Wt[(size_t)c * 256 + o] = ldin(W4, (size_t)o * FCATC + c, f32);
}

// ---------------- tiled GEMM: C[M x N2] = A[M x K] * Wt[K x N2] ----------------
// BM=BN=64, BK=16, 256 threads, 4x4 per thread. N2 % 64 == 0, M % 64 == 0.
// GUARDK: scalar A loads with k<Kdim guard (layer0, K=3); else K%16==0, float4 loads.
template <bool GUARDK>
__global__ __launch_bounds__(256) void k_gemm(const float* __restrict__ A, int lda, int aoff,
                                              const float* __restrict__ Wt,
                                              float* __restrict__ Cmat, int Kdim, int N2) {
    __shared__ float As[16][68];
    __shared__ float Bs[16][68];
    int tid = threadIdx.x;
    int tx = tid & 15, ty = tid >> 4;
    int m0 = blockIdx.y * 64, n0 = blockIdx.x * 64;
    int la_m = tid >> 2;
    int la_k = (tid & 3) * 4;
    int lb_k = tid >> 4;
    int lb_n = (tid & 15) * 4;
    float acc[4][4] = {};
    for (int k0 = 0; k0 < Kdim; k0 += 16) {
        if (GUARDK) {
            #pragma unroll
            for (int i = 0; i < 4; i++) {
                int k = k0 + la_k + i;
                As[la_k + i][la_m] = (k < Kdim) ? A[(size_t)(m0 + la_m) * lda + aoff + k] : 0.f;
            }
        } else {
            float4 f4 = *(const float4*)&A[(size_t)(m0 + la_m) * lda + aoff + k0 + la_k];
            As[la_k + 0][la_m] = f4.x; As[la_k + 1][la_m] = f4.y;
            As[la_k + 2][la_m] = f4.z; As[la_k + 3][la_m] = f4.w;
        }
        {
            float4 f4 = *(const float4*)&Wt[(size_t)(k0 + lb_k) * N2 + n0 + lb_n];
            *(float4*)&Bs[lb_k][lb_n] = f4;
        }
        __syncthreads();
        #pragma unroll
        for (int kk = 0; kk < 16; kk++) {
            float4 a = *(const float4*)&As[kk][ty * 4];
            float4 q = *(const float4*)&Bs[kk][tx * 4];
            acc[0][0] += a.x * q.x; acc[0][1] += a.x * q.y; acc[0][2] += a.x * q.z; acc[0][3] += a.x * q.w;
            acc[1][0] += a.y * q.x; acc[1][1] += a.y * q.y; acc[1][2] += a.y * q.z; acc[1][3] += a.y * q.w;
            acc[2][0] += a.z * q.x; acc[2][1] += a.z * q.y; acc[2][2] += a.z * q.z; acc[2][3] += a.z * q.w;
            acc[3][0] += a.w * q.x; acc[3][1] += a.w * q.y; acc[3][2] += a.w * q.z; acc[3][3] += a.w * q.w;
        }
        __syncthreads();
    }
    #pragma unroll
    for (int i = 0; i < 4; i++) {
        float4 o4 = make_float4(acc[i][0], acc[i][1], acc[i][2], acc[i][3]);
        *(float4*)&Cmat[(size_t)(m0 + ty * 4 + i) * N2 + n0 + tx * 4] = o4;
    }
}

// ---------------- BN stats over (B,N,K) per channel: y = u[idx]+v[n] ----------------
__global__ __launch_bounds__(256) void k_stats_edge(const float* __restrict__ UV, const int* __restrict__ idx,
                                                    float* __restrict__ gsum, float* __restrict__ gssq, int Co) {
    __shared__ int sidx[8 * KNB];
    int tid = threadIdx.x;
    int N2 = 2 * Co;
    int p0 = blockIdx.x * 8;
    if (tid < 8 * KNB) sidx[tid] = idx[p0 * KNB + tid];
    __syncthreads();
    int o0 = tid, o1 = tid + 256, o2 = tid + 512;
    bool h0 = o0 < Co, h1 = o1 < Co, h2 = o2 < Co;
    float s0 = 0, s1 = 0, s2 = 0, q0 = 0, q1 = 0, q2 = 0;
    for (int p = 0; p < 8; p++) {
        int bn = p0 + p;
        const float* vrow = UV + (size_t)bn * N2 + Co;
        float v0 = h0 ? vrow[o0] : 0.f;
        float v1 = h1 ? vrow[o1] : 0.f;
        float v2 = h2 ? vrow[o2] : 0.f;
        for (int k = 0; k < KNB; k++) {
            int m = sidx[p * KNB + k];
            const float* urow = UV + (size_t)m * N2;
            if (h0) { float y = urow[o0] + v0; s0 += y; q0 += y * y; }
            if (h1) { float y = urow[o1] + v1; s1 += y; q1 += y * y; }
            if (h2) { float y = urow[o2] + v2; s2 += y; q2 += y * y; }
        }
    }
    if (h0) { atomicAdd(&gsum[o0], s0); atomicAdd(&gssq[o0], q0); }
    if (h1) { atomicAdd(&gsum[o1], s1); atomicAdd(&gssq[o1], q1); }
    if (h2) { atomicAdd(&gsum[o2], s2); atomicAdd(&gssq[o2], q2); }
}

__global__ void k_scaleshift(const float* __restrict__ gsum, const float* __restrict__ gssq,
                             const void* __restrict__ g, const void* __restrict__ bb,
                             const int* __restrict__ flag,
                             float* __restrict__ scale, float* __restrict__ shift, int Co, float invcnt) {
    int o = blockIdx.x * 256 + threadIdx.x;
    if (o >= Co) return;
    int f32 = flag[0];
    float mean = gsum[o] * invcnt;
    float var = gssq[o] * invcnt - mean * mean;
    float sc = ldin(g, o, f32) * rsqrtf(var + 1e-5f);
    scale[o] = sc;
    shift[o] = ldin(bb, o, f32) - mean * sc;
}

// ---------------- lrelu + max over k -> fcat ----------------
__global__ __launch_bounds__(256) void k_maxpass(const float* __restrict__ UV, const int* __restrict__ idx,
                                                 const float* __restrict__ scale, const float* __restrict__ shift,
                                                 float* __restrict__ fcat, int Co, int out_off) {
    __shared__ int sidx[KNB];
    int bn = blockIdx.x;
    if (threadIdx.x < KNB) sidx[threadIdx.x] = idx[bn * KNB + threadIdx.x];
    __syncthreads();
    int N2 = 2 * Co;
    const float* vrow = UV + (size_t)bn * N2 + Co;
    for (int o = threadIdx.x; o < Co; o += 256) {
        float v = vrow[o];
        float sc = scale[o], sh = shift[o];
        float best = -INFINITY;
        for (int k = 0; k < KNB; k++) {
            int m = sidx[k];
            float y = UV[(size_t)m * N2 + o] + v;
            float z = sc * y + sh;
            z = (z >= 0.f) ? z : 0.2f * z;
            best = fmaxf(best, z);
        }
        fcat[(size_t)bn * FCATC + out_off + o] = best;
    }
}

// ---------------- final BN stats over (B,N) ----------------
__global__ void k_stats_final(const float* __restrict__ Y, float* __restrict__ gsum, float* __restrict__ gssq) {
    int o = threadIdx.x;           // 256 channels
    int p0 = blockIdx.x * 128;
    float s = 0, q = 0;
    for (int p = 0; p < 128; p++) {
        float y = Y[(size_t)(p0 + p) * 256 + o];
        s += y; q += y * y;
    }
    atomicAdd(&gsum[o], s); atomicAdd(&gssq[o], q);
}

// ---------------- feats (dtype per flag) + per-chunk max ----------------
__global__ void k_feats(const float* __restrict__ Y, const float* __restrict__ scale, const float* __restrict__ shift,
                        void* __restrict__ out, const int* __restrict__ flag, float* __restrict__ partial) {
    int o = threadIdx.x;
    int chunk = blockIdx.x;        // 64 chunks of 64 points
    int bn0 = chunk * 64;
    int f32 = flag[0];
    float sc = scale[o], sh = shift[o];
    float best = -INFINITY;
    for (int i = 0; i < 64; i++) {
        int bn = bn0 + i;
        float z = sc * Y[(size_t)bn * 256 + o] + sh;
        z = (z >= 0.f) ? z : 0.2f * z;
        size_t oi = (size_t)BATCH * 256 + (size_t)bn * 256 + o;   // feats after global_feat
        if (f32) ((float*)out)[oi] = z;
        else     ((bf16*)out)[oi] = __float2bfloat16(z);
        best = fmaxf(best, z);
    }
    partial[chunk * 256 + o] = best;
}

__global__ void k_gmax(const float* __restrict__ partial, void* __restrict__ out, const int* __restrict__ flag) {
    int o = threadIdx.x;
    int b = blockIdx.x;
    float best = -INFINITY;
    for (int c = 0; c < 32; c++) best = fmaxf(best, partial[(b * 32 + c) * 256 + o]);
    if (flag[0]) ((float*)out)[b * 256 + o] = best;
    else         ((bf16*)out)[b * 256 + o] = __float2bfloat16(best);
}

// ---------------- launch ----------------
extern "C" void kernel_launch(void* const* d_in, const int* in_sizes, int n_in,
                              void* d_out, int out_size, void* d_ws, size_t ws_size,
                              hipStream_t stream) {
    const void* x = d_in[0];

    char* ws = (char*)d_ws;
    int*   idx    = (int*)  (ws + 0);
    float* UV     = (float*)(ws + 442368);            // 4096 x 1536 f32
    float* fcat   = (float*)(ws + 25608192);          // 4096 x 1440 f32
    float* Y4     = (float*)(ws + 49201152);          // 4096 x 256 f32
    float* Wt     = (float*)(ws + 53395456);          // up to 1536 cols x 384 rows f32
    float* gsum   = (float*)(ws + 58114048);          // 1696
    float* gssq   = gsum + 1696;
    float* scales = gssq + 1696;
    float* shifts = scales + 1696;
    float* partial= (float*)(ws + 58141184);          // 64 x 256
    float* xf     = (float*)(ws + 58206720);          // 12288 f32
    int*   flag   = (int*)  (ws + 58255872);          // 1

    const int Cin[4]  = {3, 96, 192, 384};
    const int Co[4]   = {96, 192, 384, 768};
    const int ooff[4] = {0, 96, 288, 672};
    const int soff[5] = {0, 96, 288, 672, 1440};

    hipLaunchKernelGGL(k_detect, dim3(1), dim3(256), 0, stream, x, flag);
    hipLaunchKernelGGL(k_convx, dim3(48), dim3(256), 0, stream, x, flag, xf);
    hipLaunchKernelGGL(k_zero, dim3(14), dim3(256), 0, stream, gsum, 2 * 1696);
    hipLaunchKernelGGL(k_knn, dim3(NPTS), dim3(256), 0, stream, xf, idx);

    const float invcnt_edge = 1.f / (float)(NPTS * KNB);
    for (int L = 0; L < 4; L++) {
        const void* W  = d_in[1 + 3 * L];
        const void* g  = d_in[2 + 3 * L];
        const void* bb = d_in[3 + 3 * L];
        int N2 = 2 * Co[L];
        hipLaunchKernelGGL(k_wt_edge, dim3((N2 + 255) / 256, (Cin[L] + 31) / 32), dim3(256), 0, stream,
                           W, flag, Wt, Cin[L], Co[L]);
        if (L == 0) {
            hipLaunchKernelGGL((k_gemm<true>), dim3(N2 / 64, NPTS / 64), dim3(256), 0, stream,
                               xf, 3, 0, Wt, UV, Cin[L], N2);
        } else {
            hipLaunchKernelGGL((k_gemm<false>), dim3(N2 / 64, NPTS / 64), dim3(256), 0, stream,
                               fcat, FCATC, ooff[L - 1], Wt, UV, Cin[L], N2);
        }
        hipLaunchKernelGGL(k_stats_edge, dim3(NPTS / 8), dim3(256), 0, stream,
                           UV, idx, gsum + soff[L], gssq + soff[L], Co[L]);
        hipLaunchKernelGGL(k_scaleshift, dim3((Co[L] + 255) / 256), dim3(256), 0, stream,
                           gsum + soff[L], gssq + soff[L], g, bb, flag,
                           scales + soff[L], shifts + soff[L], Co[L], invcnt_edge);
        hipLaunchKernelGGL(k_maxpass, dim3(NPTS), dim3(256), 0, stream,
                           UV, idx, scales + soff[L], shifts + soff[L], fcat, Co[L], ooff[L]);
    }

    // final 1440 -> 256
    const void* W4 = d_in[13];
    const void* g4 = d_in[14];
    const void* b4 = d_in[15];
    hipLaunchKernelGGL(k_wt_final, dim3(1, (FCATC + 31) / 32), dim3(256), 0, stream, W4, flag, Wt);
    hipLaunchKernelGGL((k_gemm<false>), dim3(256 / 64, NPTS / 64), dim3(256), 0, stream,
                       fcat, FCATC, 0, Wt, Y4, FCATC, 256);
    hipLaunchKernelGGL(k_stats_final, dim3(32), dim3(256), 0, stream, Y4, gsum + soff[4], gssq + soff[4]);
    hipLaunchKernelGGL(k_scaleshift, dim3(1), dim3(256), 0, stream,
                       gsum + soff[4], gssq + soff[4], g4, b4, flag,
                       scales + soff[4], shifts + soff[4], 256, 1.f / (float)NPTS);
    hipLaunchKernelGGL(k_feats, dim3(64), dim3(256), 0, stream, Y4, scales + soff[4], shifts + soff[4],
                       d_out, flag, partial);
    hipLaunchKernelGGL(k_gmax, dim3(BATCH), dim3(256), 0, stream, partial, d_out, flag);
}

// Round 3
// 698.749 us; speedup vs baseline: 1.5277x; 1.5277x over previous
//
#include <hip/hip_runtime.h>
#include <hip/hip_bf16.h>

#define BATCH 2
#define NPB   2048
#define NPTS  4096   // BATCH*NPB
#define KNB   27
#define FCATC 1440
#define CSTRIDE 1696   // channel stride for slot partial sums (1440 + 256)
#define NSLOT 32

typedef __hip_bfloat16 bf16;

__device__ __forceinline__ float b2f(bf16 v) { return __bfloat162float(v); }

// load input element i from buffer p whose dtype is fp32 (f32=1) or bf16 (f32=0)
__device__ __forceinline__ float ldin(const void* p, size_t i, int f32) {
    return f32 ? ((const float*)p)[i] : b2f(((const bf16*)p)[i]);
}

// ---------------- dtype detect: bf16-interpret x; any huge/NaN => underlying fp32 ----------------
__global__ void k_detect(const void* __restrict__ x, int* __restrict__ flag) {
    __shared__ int s;
    if (threadIdx.x == 0) s = 0;
    __syncthreads();
    const bf16* xb = (const bf16*)x;
    int local = 0;
    for (int i = threadIdx.x; i < NPTS * 3; i += 256) {
        float v = b2f(xb[i]);
        if (!(fabsf(v) < 1e4f)) local = 1;   // catches NaN/Inf/huge
    }
    if (local) s = 1;
    __syncthreads();
    if (threadIdx.x == 0) flag[0] = s;       // 1 => fp32 underlying
}

// ---------------- convert x to fp32 ----------------
__global__ void k_convx(const void* __restrict__ x, const int* __restrict__ flag, float* __restrict__ xf) {
    int i = blockIdx.x * 256 + threadIdx.x;
    if (i >= NPTS * 3) return;
    xf[i] = ldin(x, i, flag[0]);
}

// ---------------- zero accumulators ----------------
__global__ void k_zero(float* p, int n) {
    int i = blockIdx.x * 256 + threadIdx.x;
    if (i < n) p[i] = 0.f;
}

// ---------------- KNN: top-27 by max of negative sq dist ----------------
__global__ __launch_bounds__(256) void k_knn(const float* __restrict__ x, int* __restrict__ idx) {
    __shared__ float ds[NPB];
    __shared__ float rv[4];
    __shared__ int   ri[4];
    int bn = blockIdx.x;            // 0..4095
    int b = bn >> 11, n = bn & (NPB - 1);
    const float* xb = x + (size_t)b * NPB * 3;
    float cx = xb[n * 3 + 0];
    float cy = xb[n * 3 + 1];
    float cz = xb[n * 3 + 2];
    float cc = cx * cx + cy * cy + cz * cz;
    for (int m = threadIdx.x; m < NPB; m += 256) {
        float mx = xb[m * 3 + 0];
        float my = xb[m * 3 + 1];
        float mz = xb[m * 3 + 2];
        float mm = mx * mx + my * my + mz * mz;
        float dot = cx * mx + cy * my + cz * mz;
        ds[m] = 2.f * dot - cc - mm;
    }
    __syncthreads();
    int lane = threadIdx.x & 63, wv = threadIdx.x >> 6;
    for (int kk = 0; kk < KNB; kk++) {
        float bv = -INFINITY; int bi = 0x7fffffff;
        for (int m = threadIdx.x; m < NPB; m += 256) {
            float v = ds[m];
            if (v > bv || (v == bv && m < bi)) { bv = v; bi = m; }
        }
        for (int off = 32; off > 0; off >>= 1) {
            float ov = __shfl_down(bv, off);
            int   oi = __shfl_down(bi, off);
            if (ov > bv || (ov == bv && oi < bi)) { bv = ov; bi = oi; }
        }
        if (lane == 0) { rv[wv] = bv; ri[wv] = bi; }
        __syncthreads();
        if (threadIdx.x == 0) {
            float fv = rv[0]; int fi = ri[0];
            for (int w = 1; w < 4; w++)
                if (rv[w] > fv || (rv[w] == fv && ri[w] < fi)) { fv = rv[w]; fi = ri[w]; }
            if (fi < 0 || fi >= NPB) fi = 0;     // safety: never OOB
            idx[bn * KNB + kk] = b * NPB + fi;   // global point id
            ds[fi] = -INFINITY;
        }
        __syncthreads();
    }
}

// ---------------- W transpose + u/v transform ----------------
// Wt[c*N2 + o] : o<Co -> W[o, c] (left);  o>=Co -> W[o-Co, Cin+c] - W[o-Co, c]
__global__ void k_wt_edge(const void* __restrict__ W, const int* __restrict__ flag,
                          float* __restrict__ Wt, int Cin, int Co) {
    int o = blockIdx.x * 256 + threadIdx.x;
    int N2 = 2 * Co;
    if (o >= N2) return;
    int f32 = flag[0];
    int c0 = blockIdx.y * 32;
    int c1 = c0 + 32; if (c1 > Cin) c1 = Cin;
    if (o < Co) {
        for (int c = c0; c < c1; c++)
            Wt[(size_t)c * N2 + o] = ldin(W, (size_t)o * 2 * Cin + c, f32);
    } else {
        int oo = o - Co;
        for (int c = c0; c < c1; c++)
            Wt[(size_t)c * N2 + o] = ldin(W, (size_t)oo * 2 * Cin + Cin + c, f32)
                                   - ldin(W, (size_t)oo * 2 * Cin + c, f32);
    }
}

__global__ void k_wt_final(const void* __restrict__ W4, const int* __restrict__ flag, float* __restrict__ Wt) {
    int o = threadIdx.x;                 // 0..255
    int f32 = flag[0];
    int c0 = blockIdx.y * 32;
    int c1 = c0 + 32; if (c1 > FCATC) c1 = FCATC;
    for (int c = c0; c < c1; c++)
        Wt[(size_t)c * 256 + o] = ldin(W4, (size_t)o * FCATC + c, f32);
}

// ---------------- tiled GEMM: C[M x N2] = A[M x K] * Wt[K x N2] ----------------
// BM=BN=64, BK=16, 256 threads, 4x4 per thread. N2 % 64 == 0, M % 64 == 0.
// GUARDK: scalar A loads with k<Kdim guard (layer0, K=3); else K%16==0, float4 loads.
template <bool GUARDK>
__global__ __launch_bounds__(256) void k_gemm(const float* __restrict__ A, int lda, int aoff,
                                              const float* __restrict__ Wt,
                                              float* __restrict__ Cmat, int Kdim, int N2) {
    __shared__ float As[16][68];
    __shared__ float Bs[16][68];
    int tid = threadIdx.x;
    int tx = tid & 15, ty = tid >> 4;
    int m0 = blockIdx.y * 64, n0 = blockIdx.x * 64;
    int la_m = tid >> 2;
    int la_k = (tid & 3) * 4;
    int lb_k = tid >> 4;
    int lb_n = (tid & 15) * 4;
    float acc[4][4] = {};
    for (int k0 = 0; k0 < Kdim; k0 += 16) {
        if (GUARDK) {
            #pragma unroll
            for (int i = 0; i < 4; i++) {
                int k = k0 + la_k + i;
                As[la_k + i][la_m] = (k < Kdim) ? A[(size_t)(m0 + la_m) * lda + aoff + k] : 0.f;
            }
        } else {
            float4 f4 = *(const float4*)&A[(size_t)(m0 + la_m) * lda + aoff + k0 + la_k];
            As[la_k + 0][la_m] = f4.x; As[la_k + 1][la_m] = f4.y;
            As[la_k + 2][la_m] = f4.z; As[la_k + 3][la_m] = f4.w;
        }
        {
            float4 f4 = *(const float4*)&Wt[(size_t)(k0 + lb_k) * N2 + n0 + lb_n];
            *(float4*)&Bs[lb_k][lb_n] = f4;
        }
        __syncthreads();
        #pragma unroll
        for (int kk = 0; kk < 16; kk++) {
            float4 a = *(const float4*)&As[kk][ty * 4];
            float4 q = *(const float4*)&Bs[kk][tx * 4];
            acc[0][0] += a.x * q.x; acc[0][1] += a.x * q.y; acc[0][2] += a.x * q.z; acc[0][3] += a.x * q.w;
            acc[1][0] += a.y * q.x; acc[1][1] += a.y * q.y; acc[1][2] += a.y * q.z; acc[1][3] += a.y * q.w;
            acc[2][0] += a.z * q.x; acc[2][1] += a.z * q.y; acc[2][2] += a.z * q.z; acc[2][3] += a.z * q.w;
            acc[3][0] += a.w * q.x; acc[3][1] += a.w * q.y; acc[3][2] += a.w * q.z; acc[3][3] += a.w * q.w;
        }
        __syncthreads();
    }
    #pragma unroll
    for (int i = 0; i < 4; i++) {
        float4 o4 = make_float4(acc[i][0], acc[i][1], acc[i][2], acc[i][3]);
        *(float4*)&Cmat[(size_t)(m0 + ty * 4 + i) * N2 + n0 + tx * 4] = o4;
    }
}

// ---------------- fused gather: per point, per channel -> ymax, ymin, sum, sumsq ----------------
// One block per point. ymax -> fcat slice (pre-BN), ymin -> own v-half of UV (already consumed),
// sum/sumsq -> 32-slot partial accumulators (atomic, slot = bn&31).
__global__ __launch_bounds__(256) void k_gather(float* __restrict__ UV, const int* __restrict__ idx,
                                                float* __restrict__ fcat,
                                                float* __restrict__ ssum, float* __restrict__ ssq,
                                                int Co, int out_off) {
    __shared__ int srow[KNB];   // precomputed row base offsets (elements)
    int bn = blockIdx.x;
    int tid = threadIdx.x;
    int N2 = 2 * Co;
    if (tid < KNB) srow[tid] = idx[bn * KNB + tid] * N2;
    __syncthreads();
    int slot = bn & (NSLOT - 1);
    for (int o = tid; o < Co; o += 256) {
        float v = UV[(size_t)bn * N2 + Co + o];
        float ymax = -INFINITY, ymin = INFINITY, s = 0.f, q = 0.f;
        #pragma unroll
        for (int k = 0; k < KNB; k++) {
            float y = UV[(size_t)srow[k] + o] + v;
            ymax = fmaxf(ymax, y);
            ymin = fminf(ymin, y);
            s += y; q += y * y;
        }
        fcat[(size_t)bn * FCATC + out_off + o] = ymax;     // pre-BN max
        UV[(size_t)bn * N2 + Co + o] = ymin;               // stash ymin in own v slot
        atomicAdd(&ssum[slot * CSTRIDE + o], s);
        atomicAdd(&ssq [slot * CSTRIDE + o], q);
    }
}

// ---------------- scale/shift from 32-slot partials ----------------
__global__ void k_scaleshift(const float* __restrict__ ssum, const float* __restrict__ ssq,
                             const void* __restrict__ g, const void* __restrict__ bb,
                             const int* __restrict__ flag,
                             float* __restrict__ scale, float* __restrict__ shift, int Co, float invcnt) {
    int o = blockIdx.x * 256 + threadIdx.x;
    if (o >= Co) return;
    int f32 = flag[0];
    float s = 0.f, q = 0.f;
    for (int c = 0; c < NSLOT; c++) { s += ssum[c * CSTRIDE + o]; q += ssq[c * CSTRIDE + o]; }
    float mean = s * invcnt;
    float var = q * invcnt - mean * mean;
    float sc = ldin(g, o, f32) * rsqrtf(var + 1e-5f);
    scale[o] = sc;
    shift[o] = ldin(bb, o, f32) - mean * sc;
}

// ---------------- apply BN + lrelu to the pooled value (in place in fcat) ----------------
__global__ __launch_bounds__(256) void k_apply(const float* __restrict__ UV,
                                               const float* __restrict__ scale, const float* __restrict__ shift,
                                               float* __restrict__ fcat, int Co, int out_off) {
    int bn = blockIdx.x;
    int N2 = 2 * Co;
    for (int o = threadIdx.x; o < Co; o += 256) {
        float sc = scale[o], sh = shift[o];
        float y = (sc >= 0.f) ? fcat[(size_t)bn * FCATC + out_off + o]
                              : UV[(size_t)bn * N2 + Co + o];      // ymin if negative scale
        float z = sc * y + sh;
        z = (z >= 0.f) ? z : 0.2f * z;
        fcat[(size_t)bn * FCATC + out_off + o] = z;
    }
}

// ---------------- final BN stats over (B,N): direct per-slot writes ----------------
__global__ void k_stats_final(const float* __restrict__ Y, float* __restrict__ ssum, float* __restrict__ ssq) {
    int o = threadIdx.x;           // 256 channels
    int p0 = blockIdx.x * 128;     // 32 blocks x 128 points
    float s = 0, q = 0;
    for (int p = 0; p < 128; p++) {
        float y = Y[(size_t)(p0 + p) * 256 + o];
        s += y; q += y * y;
    }
    ssum[blockIdx.x * CSTRIDE + o] = s;
    ssq [blockIdx.x * CSTRIDE + o] = q;
}

// ---------------- feats (dtype per flag) + per-chunk max ----------------
__global__ void k_feats(const float* __restrict__ Y, const float* __restrict__ scale, const float* __restrict__ shift,
                        void* __restrict__ out, const int* __restrict__ flag, float* __restrict__ partial) {
    int o = threadIdx.x;
    int chunk = blockIdx.x;        // 64 chunks of 64 points
    int bn0 = chunk * 64;
    int f32 = flag[0];
    float sc = scale[o], sh = shift[o];
    float best = -INFINITY;
    for (int i = 0; i < 64; i++) {
        int bn = bn0 + i;
        float z = sc * Y[(size_t)bn * 256 + o] + sh;
        z = (z >= 0.f) ? z : 0.2f * z;
        size_t oi = (size_t)BATCH * 256 + (size_t)bn * 256 + o;   // feats after global_feat
        if (f32) ((float*)out)[oi] = z;
        else     ((bf16*)out)[oi] = __float2bfloat16(z);
        best = fmaxf(best, z);
    }
    partial[chunk * 256 + o] = best;
}

__global__ void k_gmax(const float* __restrict__ partial, void* __restrict__ out, const int* __restrict__ flag) {
    int o = threadIdx.x;
    int b = blockIdx.x;
    float best = -INFINITY;
    for (int c = 0; c < 32; c++) best = fmaxf(best, partial[(b * 32 + c) * 256 + o]);
    if (flag[0]) ((float*)out)[b * 256 + o] = best;
    else         ((bf16*)out)[b * 256 + o] = __float2bfloat16(best);
}

// ---------------- launch ----------------
extern "C" void kernel_launch(void* const* d_in, const int* in_sizes, int n_in,
                              void* d_out, int out_size, void* d_ws, size_t ws_size,
                              hipStream_t stream) {
    const void* x = d_in[0];

    char* ws = (char*)d_ws;
    int*   idx    = (int*)  (ws + 0);
    float* UV     = (float*)(ws + 442368);            // 4096 x 1536 f32
    float* fcat   = (float*)(ws + 25608192);          // 4096 x 1440 f32
    float* Y4     = (float*)(ws + 49201152);          // 4096 x 256 f32
    float* Wt     = (float*)(ws + 53395456);          // up to 1440x256 / 384x1536 f32 (<= 2.36 MB)
    float* slots  = (float*)(ws + 55795456);          // 2 x 32 x 1696 f32 (sum then sq)
    float* ssum   = slots;
    float* ssq    = slots + NSLOT * CSTRIDE;
    float* scales = (float*)(ws + 58114048);          // 1696
    float* shifts = scales + 1696;
    float* partial= (float*)(ws + 58141184);          // 64 x 256
    float* xf     = (float*)(ws + 58206720);          // 12288 f32
    int*   flag   = (int*)  (ws + 58255872);          // 1

    const int Cin[4]  = {3, 96, 192, 384};
    const int Co[4]   = {96, 192, 384, 768};
    const int ooff[4] = {0, 96, 288, 672};
    const int soff[5] = {0, 96, 288, 672, 1440};

    hipLaunchKernelGGL(k_detect, dim3(1), dim3(256), 0, stream, x, flag);
    hipLaunchKernelGGL(k_convx, dim3(48), dim3(256), 0, stream, x, flag, xf);
    hipLaunchKernelGGL(k_zero, dim3((2 * NSLOT * CSTRIDE + 255) / 256), dim3(256), 0, stream,
                       slots, 2 * NSLOT * CSTRIDE);
    hipLaunchKernelGGL(k_knn, dim3(NPTS), dim3(256), 0, stream, xf, idx);

    const float invcnt_edge = 1.f / (float)(NPTS * KNB);
    for (int L = 0; L < 4; L++) {
        const void* W  = d_in[1 + 3 * L];
        const void* g  = d_in[2 + 3 * L];
        const void* bb = d_in[3 + 3 * L];
        int N2 = 2 * Co[L];
        hipLaunchKernelGGL(k_wt_edge, dim3((N2 + 255) / 256, (Cin[L] + 31) / 32), dim3(256), 0, stream,
                           W, flag, Wt, Cin[L], Co[L]);
        if (L == 0) {
            hipLaunchKernelGGL((k_gemm<true>), dim3(N2 / 64, NPTS / 64), dim3(256), 0, stream,
                               xf, 3, 0, Wt, UV, Cin[L], N2);
        } else {
            hipLaunchKernelGGL((k_gemm<false>), dim3(N2 / 64, NPTS / 64), dim3(256), 0, stream,
                               fcat, FCATC, ooff[L - 1], Wt, UV, Cin[L], N2);
        }
        hipLaunchKernelGGL(k_gather, dim3(NPTS), dim3(256), 0, stream,
                           UV, idx, fcat, ssum + soff[L], ssq + soff[L], Co[L], ooff[L]);
        hipLaunchKernelGGL(k_scaleshift, dim3((Co[L] + 255) / 256), dim3(256), 0, stream,
                           ssum + soff[L], ssq + soff[L], g, bb, flag,
                           scales + soff[L], shifts + soff[L], Co[L], invcnt_edge);
        hipLaunchKernelGGL(k_apply, dim3(NPTS), dim3(256), 0, stream,
                           UV, scales + soff[L], shifts + soff[L], fcat, Co[L], ooff[L]);
    }

    // final 1440 -> 256
    const void* W4 = d_in[13];
    const void* g4 = d_in[14];
    const void* b4 = d_in[15];
    hipLaunchKernelGGL(k_wt_final, dim3(1, (FCATC + 31) / 32), dim3(256), 0, stream, W4, flag, Wt);
    hipLaunchKernelGGL((k_gemm<false>), dim3(256 / 64, NPTS / 64), dim3(256), 0, stream,
                       fcat, FCATC, 0, Wt, Y4, FCATC, 256);
    hipLaunchKernelGGL(k_stats_final, dim3(32), dim3(256), 0, stream, Y4, ssum + soff[4], ssq + soff[4]);
    hipLaunchKernelGGL(k_scaleshift, dim3(1), dim3(256), 0, stream,
                       ssum + soff[4], ssq + soff[4], g4, b4, flag,
                       scales + soff[4], shifts + soff[4], 256, 1.f / (float)NPTS);
    hipLaunchKernelGGL(k_feats, dim3(64), dim3(256), 0, stream, Y4, scales + soff[4], shifts + soff[4],
                       d_out, flag, partial);
    hipLaunchKernelGGL(k_gmax, dim3(BATCH), dim3(256), 0, stream, partial, d_out, flag);
}

// Round 4
// 593.400 us; speedup vs baseline: 1.7989x; 1.1775x over previous
//
#include <hip/hip_runtime.h>
#include <hip/hip_bf16.h>

#define BATCH 2
#define NPB   2048
#define NPTS  4096   // BATCH*NPB
#define KNB   27
#define FCATC 1440
#define CSTRIDE 1696   // channel stride for slot partial sums (1440 + 256)
#define NSLOT 32

typedef __hip_bfloat16 bf16;

__device__ __forceinline__ float b2f(bf16 v) { return __bfloat162float(v); }

// load input element i from buffer p whose dtype is fp32 (f32=1) or bf16 (f32=0)
__device__ __forceinline__ float ldin(const void* p, size_t i, int f32) {
    return f32 ? ((const float*)p)[i] : b2f(((const bf16*)p)[i]);
}

// ---------------- dtype detect: bf16-interpret x; any huge/NaN => underlying fp32 ----------------
__global__ void k_detect(const void* __restrict__ x, int* __restrict__ flag) {
    __shared__ int s;
    if (threadIdx.x == 0) s = 0;
    __syncthreads();
    const bf16* xb = (const bf16*)x;
    int local = 0;
    for (int i = threadIdx.x; i < NPTS * 3; i += 256) {
        float v = b2f(xb[i]);
        if (!(fabsf(v) < 1e4f)) local = 1;   // catches NaN/Inf/huge
    }
    if (local) s = 1;
    __syncthreads();
    if (threadIdx.x == 0) flag[0] = s;       // 1 => fp32 underlying
}

// ---------------- convert x to fp32 ----------------
__global__ void k_convx(const void* __restrict__ x, const int* __restrict__ flag, float* __restrict__ xf) {
    int i = blockIdx.x * 256 + threadIdx.x;
    if (i >= NPTS * 3) return;
    xf[i] = ldin(x, i, flag[0]);
}

// ---------------- zero accumulators ----------------
__global__ void k_zero(float* p, int n) {
    int i = blockIdx.x * 256 + threadIdx.x;
    if (i < n) p[i] = 0.f;
}

// ---------------- KNN via radix-select: top-27 by max of negative sq dist ----------------
// One block per point. Keys register-resident; 4x 8-bit radix passes with per-wave
// bank-padded LDS histograms; ties resolved to smallest index (lax.top_k set semantics).
__global__ __launch_bounds__(256) void k_knn(const float* __restrict__ x, int* __restrict__ idx) {
    __shared__ uint hist4[4][260];   // per-wave copies, padded to distinct banks
    __shared__ uint hist[256];
    __shared__ int  tix[NPB];
    __shared__ uint s_phigh;
    __shared__ int  s_rem, s_outcnt, s_tiecnt;

    int bn = blockIdx.x, b = bn >> 11, n = bn & (NPB - 1);
    int tid = threadIdx.x;
    int wv = tid >> 6;
    const float* xb = x + (size_t)b * NPB * 3;
    float cx = xb[n * 3 + 0], cy = xb[n * 3 + 1], cz = xb[n * 3 + 2];
    float cc = cx * cx + cy * cy + cz * cz;

    // 8 distances per thread, converted to order-preserving uint keys (larger d => larger u)
    uint u[8];
    #pragma unroll
    for (int j = 0; j < 8; j++) {
        int m = j * 256 + tid;
        float mx = xb[m * 3 + 0], my = xb[m * 3 + 1], mz = xb[m * 3 + 2];
        float d = 2.f * (cx * mx + cy * my + cz * mz) - cc - (mx * mx + my * my + mz * mz);
        uint s = __float_as_uint(d);
        u[j] = (s & 0x80000000u) ? ~s : (s | 0x80000000u);
    }
    if (tid == 0) { s_phigh = 0; s_rem = KNB; s_outcnt = 0; s_tiecnt = 0; }

    for (int pass = 0; pass < 4; pass++) {
        int shift = 24 - pass * 8;
        // zero histograms
        hist[tid] = 0;
        for (int i = tid; i < 4 * 260; i += 256) ((uint*)hist4)[i] = 0;
        __syncthreads();
        uint phigh = s_phigh;
        #pragma unroll
        for (int j = 0; j < 8; j++) {
            bool in = (pass == 0) || ((u[j] >> (shift + 8)) == phigh);
            if (in) atomicAdd(&hist4[wv][(u[j] >> shift) & 0xFFu], 1u);
        }
        __syncthreads();
        hist[tid] = hist4[0][tid] + hist4[1][tid] + hist4[2][tid] + hist4[3][tid];
        __syncthreads();
        if (tid < 64) {
            int L = tid;
            uint c0 = hist[L * 4 + 0], c1 = hist[L * 4 + 1], c2 = hist[L * 4 + 2], c3 = hist[L * 4 + 3];
            uint s = c0 + c1 + c2 + c3;
            uint acc = s;
            #pragma unroll
            for (int off = 1; off < 64; off <<= 1) {
                uint t = __shfl_down(acc, off);
                if (L + off < 64) acc += t;
            }
            // acc = sum_{j>=L}; excl = sum_{j>L}
            uint excl = acc - s;
            int rem = s_rem;
            if ((int)excl < rem && (int)acc >= rem) {   // exactly one lane
                uint cs[4] = { c0, c1, c2, c3 };
                uint cum = excl;
                int bsel = 0; uint hb = 0;
                #pragma unroll
                for (int q = 3; q >= 0; q--) {
                    if ((int)cum < rem && (int)(cum + cs[q]) >= rem && hb == 0u && bsel == 0) {
                        // first crossing from high bin down
                        bsel = L * 4 + q; hb = cs[q]; cum += cs[q];
                    } else if (bsel == 0 && hb == 0u) {
                        cum += cs[q];
                    }
                }
                int strictlyAbove = (int)(cum - hb);
                s_rem = rem - strictlyAbove;
                s_phigh = (phigh << 8) | (uint)bsel;
            }
        }
        __syncthreads();
    }

    uint T = s_phigh;   // exact 32-bit key of the 27th largest
    // collection: strictly greater go straight out; ties gathered
    #pragma unroll
    for (int j = 0; j < 8; j++) {
        int m = j * 256 + tid;
        if (u[j] > T) {
            int p = atomicAdd(&s_outcnt, 1);
            idx[bn * KNB + p] = b * NPB + m;
        } else if (u[j] == T) {
            int p = atomicAdd(&s_tiecnt, 1);
            tix[p] = m;
        }
    }
    __syncthreads();
    int outcnt = s_outcnt, rem = s_rem, tiecnt = s_tiecnt;
    if (tiecnt == rem) {
        if (tid < rem) idx[bn * KNB + outcnt + tid] = b * NPB + tix[tid];
    } else if (tid == 0) {
        // rare: pick the `rem` smallest indices among ties
        for (int t = 0; t < rem; t++) {
            int bi = 0;
            for (int q = 1; q < tiecnt; q++) if (tix[q] < tix[bi]) bi = q;
            idx[bn * KNB + outcnt + t] = b * NPB + tix[bi];
            tix[bi] = 0x7fffffff;
        }
    }
}

// ---------------- W transpose + u/v transform ----------------
// Wt[c*N2 + o] : o<Co -> W[o, c] (left);  o>=Co -> W[o-Co, Cin+c] - W[o-Co, c]
__global__ void k_wt_edge(const void* __restrict__ W, const int* __restrict__ flag,
                          float* __restrict__ Wt, int Cin, int Co) {
    int o = blockIdx.x * 256 + threadIdx.x;
    int N2 = 2 * Co;
    if (o >= N2) return;
    int f32 = flag[0];
    int c0 = blockIdx.y * 32;
    int c1 = c0 + 32; if (c1 > Cin) c1 = Cin;
    if (o < Co) {
        for (int c = c0; c < c1; c++)
            Wt[(size_t)c * N2 + o] = ldin(W, (size_t)o * 2 * Cin + c, f32);
    } else {
        int oo = o - Co;
        for (int c = c0; c < c1; c++)
            Wt[(size_t)c * N2 + o] = ldin(W, (size_t)oo * 2 * Cin + Cin + c, f32)
                                   - ldin(W, (size_t)oo * 2 * Cin + c, f32);
    }
}

__global__ void k_wt_final(const void* __restrict__ W4, const int* __restrict__ flag, float* __restrict__ Wt) {
    int o = threadIdx.x;                 // 0..255
    int f32 = flag[0];
    int c0 = blockIdx.y * 32;
    int c1 = c0 + 32; if (c1 > FCATC) c1 = FCATC;
    for (int c = c0; c < c1; c++)
        Wt[(size_t)c * 256 + o] = ldin(W4, (size_t)o * FCATC + c, f32);
}

// ---------------- tiled GEMM: C[M x N2] = A[M x K] * Wt[K x N2] ----------------
// BM=BN=64, BK=16, 256 threads, 4x4 per thread. N2 % 64 == 0, M % 64 == 0.
// GUARDK: scalar A loads with k<Kdim guard (layer0, K=3); else K%16==0, float4 loads.
template <bool GUARDK>
__global__ __launch_bounds__(256) void k_gemm(const float* __restrict__ A, int lda, int aoff,
                                              const float* __restrict__ Wt,
                                              float* __restrict__ Cmat, int Kdim, int N2) {
    __shared__ float As[16][68];
    __shared__ float Bs[16][68];
    int tid = threadIdx.x;
    int tx = tid & 15, ty = tid >> 4;
    int m0 = blockIdx.y * 64, n0 = blockIdx.x * 64;
    int la_m = tid >> 2;
    int la_k = (tid & 3) * 4;
    int lb_k = tid >> 4;
    int lb_n = (tid & 15) * 4;
    float acc[4][4] = {};
    for (int k0 = 0; k0 < Kdim; k0 += 16) {
        if (GUARDK) {
            #pragma unroll
            for (int i = 0; i < 4; i++) {
                int k = k0 + la_k + i;
                As[la_k + i][la_m] = (k < Kdim) ? A[(size_t)(m0 + la_m) * lda + aoff + k] : 0.f;
            }
        } else {
            float4 f4 = *(const float4*)&A[(size_t)(m0 + la_m) * lda + aoff + k0 + la_k];
            As[la_k + 0][la_m] = f4.x; As[la_k + 1][la_m] = f4.y;
            As[la_k + 2][la_m] = f4.z; As[la_k + 3][la_m] = f4.w;
        }
        {
            float4 f4 = *(const float4*)&Wt[(size_t)(k0 + lb_k) * N2 + n0 + lb_n];
            *(float4*)&Bs[lb_k][lb_n] = f4;
        }
        __syncthreads();
        #pragma unroll
        for (int kk = 0; kk < 16; kk++) {
            float4 a = *(const float4*)&As[kk][ty * 4];
            float4 q = *(const float4*)&Bs[kk][tx * 4];
            acc[0][0] += a.x * q.x; acc[0][1] += a.x * q.y; acc[0][2] += a.x * q.z; acc[0][3] += a.x * q.w;
            acc[1][0] += a.y * q.x; acc[1][1] += a.y * q.y; acc[1][2] += a.y * q.z; acc[1][3] += a.y * q.w;
            acc[2][0] += a.z * q.x; acc[2][1] += a.z * q.y; acc[2][2] += a.z * q.z; acc[2][3] += a.z * q.w;
            acc[3][0] += a.w * q.x; acc[3][1] += a.w * q.y; acc[3][2] += a.w * q.z; acc[3][3] += a.w * q.w;
        }
        __syncthreads();
    }
    #pragma unroll
    for (int i = 0; i < 4; i++) {
        float4 o4 = make_float4(acc[i][0], acc[i][1], acc[i][2], acc[i][3]);
        *(float4*)&Cmat[(size_t)(m0 + ty * 4 + i) * N2 + n0 + tx * 4] = o4;
    }
}

// ---------------- fused gather: per point, per channel -> ymax, ymin, sum, sumsq ----------------
__global__ __launch_bounds__(256) void k_gather(float* __restrict__ UV, const int* __restrict__ idx,
                                                float* __restrict__ fcat,
                                                float* __restrict__ ssum, float* __restrict__ ssq,
                                                int Co, int out_off) {
    __shared__ int srow[KNB];   // precomputed row base offsets (elements)
    int bn = blockIdx.x;
    int tid = threadIdx.x;
    int N2 = 2 * Co;
    if (tid < KNB) srow[tid] = idx[bn * KNB + tid] * N2;
    __syncthreads();
    int slot = bn & (NSLOT - 1);
    for (int o = tid; o < Co; o += 256) {
        float v = UV[(size_t)bn * N2 + Co + o];
        float ymax = -INFINITY, ymin = INFINITY, s = 0.f, q = 0.f;
        #pragma unroll
        for (int k = 0; k < KNB; k++) {
            float y = UV[(size_t)srow[k] + o] + v;
            ymax = fmaxf(ymax, y);
            ymin = fminf(ymin, y);
            s += y; q += y * y;
        }
        fcat[(size_t)bn * FCATC + out_off + o] = ymax;     // pre-BN max
        UV[(size_t)bn * N2 + Co + o] = ymin;               // stash ymin in own v slot
        atomicAdd(&ssum[slot * CSTRIDE + o], s);
        atomicAdd(&ssq [slot * CSTRIDE + o], q);
    }
}

// ---------------- scale/shift from 32-slot partials ----------------
__global__ void k_scaleshift(const float* __restrict__ ssum, const float* __restrict__ ssq,
                             const void* __restrict__ g, const void* __restrict__ bb,
                             const int* __restrict__ flag,
                             float* __restrict__ scale, float* __restrict__ shift, int Co, float invcnt) {
    int o = blockIdx.x * 256 + threadIdx.x;
    if (o >= Co) return;
    int f32 = flag[0];
    float s = 0.f, q = 0.f;
    for (int c = 0; c < NSLOT; c++) { s += ssum[c * CSTRIDE + o]; q += ssq[c * CSTRIDE + o]; }
    float mean = s * invcnt;
    float var = q * invcnt - mean * mean;
    float sc = ldin(g, o, f32) * rsqrtf(var + 1e-5f);
    scale[o] = sc;
    shift[o] = ldin(bb, o, f32) - mean * sc;
}

// ---------------- apply BN + lrelu to the pooled value (in place in fcat) ----------------
__global__ __launch_bounds__(256) void k_apply(const float* __restrict__ UV,
                                               const float* __restrict__ scale, const float* __restrict__ shift,
                                               float* __restrict__ fcat, int Co, int out_off) {
    int bn = blockIdx.x;
    int N2 = 2 * Co;
    for (int o = threadIdx.x; o < Co; o += 256) {
        float sc = scale[o], sh = shift[o];
        float y = (sc >= 0.f) ? fcat[(size_t)bn * FCATC + out_off + o]
                              : UV[(size_t)bn * N2 + Co + o];      // ymin if negative scale
        float z = sc * y + sh;
        z = (z >= 0.f) ? z : 0.2f * z;
        fcat[(size_t)bn * FCATC + out_off + o] = z;
    }
}

// ---------------- final BN stats over (B,N): direct per-slot writes ----------------
__global__ void k_stats_final(const float* __restrict__ Y, float* __restrict__ ssum, float* __restrict__ ssq) {
    int o = threadIdx.x;           // 256 channels
    int p0 = blockIdx.x * 128;     // 32 blocks x 128 points
    float s = 0, q = 0;
    for (int p = 0; p < 128; p++) {
        float y = Y[(size_t)(p0 + p) * 256 + o];
        s += y; q += y * y;
    }
    ssum[blockIdx.x * CSTRIDE + o] = s;
    ssq [blockIdx.x * CSTRIDE + o] = q;
}

// ---------------- feats (dtype per flag) + per-chunk max ----------------
__global__ void k_feats(const float* __restrict__ Y, const float* __restrict__ scale, const float* __restrict__ shift,
                        void* __restrict__ out, const int* __restrict__ flag, float* __restrict__ partial) {
    int o = threadIdx.x;
    int chunk = blockIdx.x;        // 64 chunks of 64 points
    int bn0 = chunk * 64;
    int f32 = flag[0];
    float sc = scale[o], sh = shift[o];
    float best = -INFINITY;
    for (int i = 0; i < 64; i++) {
        int bn = bn0 + i;
        float z = sc * Y[(size_t)bn * 256 + o] + sh;
        z = (z >= 0.f) ? z : 0.2f * z;
        size_t oi = (size_t)BATCH * 256 + (size_t)bn * 256 + o;   // feats after global_feat
        if (f32) ((float*)out)[oi] = z;
        else     ((bf16*)out)[oi] = __float2bfloat16(z);
        best = fmaxf(best, z);
    }
    partial[chunk * 256 + o] = best;
}

__global__ void k_gmax(const float* __restrict__ partial, void* __restrict__ out, const int* __restrict__ flag) {
    int o = threadIdx.x;
    int b = blockIdx.x;
    float best = -INFINITY;
    for (int c = 0; c < 32; c++) best = fmaxf(best, partial[(b * 32 + c) * 256 + o]);
    if (flag[0]) ((float*)out)[b * 256 + o] = best;
    else         ((bf16*)out)[b * 256 + o] = __float2bfloat16(best);
}

// ---------------- launch ----------------
extern "C" void kernel_launch(void* const* d_in, const int* in_sizes, int n_in,
                              void* d_out, int out_size, void* d_ws, size_t ws_size,
                              hipStream_t stream) {
    const void* x = d_in[0];

    char* ws = (char*)d_ws;
    int*   idx    = (int*)  (ws + 0);
    float* UV     = (float*)(ws + 442368);            // 4096 x 1536 f32
    float* fcat   = (float*)(ws + 25608192);          // 4096 x 1440 f32
    float* Y4     = (float*)(ws + 49201152);          // 4096 x 256 f32
    float* Wt     = (float*)(ws + 53395456);          // up to 1440x256 / 384x1536 f32 (<= 2.36 MB)
    float* slots  = (float*)(ws + 55795456);          // 2 x 32 x 1696 f32 (sum then sq)
    float* ssum   = slots;
    float* ssq    = slots + NSLOT * CSTRIDE;
    float* scales = (float*)(ws + 58114048);          // 1696
    float* shifts = scales + 1696;
    float* partial= (float*)(ws + 58141184);          // 64 x 256
    float* xf     = (float*)(ws + 58206720);          // 12288 f32
    int*   flag   = (int*)  (ws + 58255872);          // 1

    const int Cin[4]  = {3, 96, 192, 384};
    const int Co[4]   = {96, 192, 384, 768};
    const int ooff[4] = {0, 96, 288, 672};
    const int soff[5] = {0, 96, 288, 672, 1440};

    hipLaunchKernelGGL(k_detect, dim3(1), dim3(256), 0, stream, x, flag);
    hipLaunchKernelGGL(k_convx, dim3(48), dim3(256), 0, stream, x, flag, xf);
    hipLaunchKernelGGL(k_zero, dim3((2 * NSLOT * CSTRIDE + 255) / 256), dim3(256), 0, stream,
                       slots, 2 * NSLOT * CSTRIDE);
    hipLaunchKernelGGL(k_knn, dim3(NPTS), dim3(256), 0, stream, xf, idx);

    const float invcnt_edge = 1.f / (float)(NPTS * KNB);
    for (int L = 0; L < 4; L++) {
        const void* W  = d_in[1 + 3 * L];
        const void* g  = d_in[2 + 3 * L];
        const void* bb = d_in[3 + 3 * L];
        int N2 = 2 * Co[L];
        hipLaunchKernelGGL(k_wt_edge, dim3((N2 + 255) / 256, (Cin[L] + 31) / 32), dim3(256), 0, stream,
                           W, flag, Wt, Cin[L], Co[L]);
        if (L == 0) {
            hipLaunchKernelGGL((k_gemm<true>), dim3(N2 / 64, NPTS / 64), dim3(256), 0, stream,
                               xf, 3, 0, Wt, UV, Cin[L], N2);
        } else {
            hipLaunchKernelGGL((k_gemm<false>), dim3(N2 / 64, NPTS / 64), dim3(256), 0, stream,
                               fcat, FCATC, ooff[L - 1], Wt, UV, Cin[L], N2);
        }
        hipLaunchKernelGGL(k_gather, dim3(NPTS), dim3(256), 0, stream,
                           UV, idx, fcat, ssum + soff[L], ssq + soff[L], Co[L], ooff[L]);
        hipLaunchKernelGGL(k_scaleshift, dim3((Co[L] + 255) / 256), dim3(256), 0, stream,
                           ssum + soff[L], ssq + soff[L], g, bb, flag,
                           scales + soff[L], shifts + soff[L], Co[L], invcnt_edge);
        hipLaunchKernelGGL(k_apply, dim3(NPTS), dim3(256), 0, stream,
                           UV, scales + soff[L], shifts + soff[L], fcat, Co[L], ooff[L]);
    }

    // final 1440 -> 256
    const void* W4 = d_in[13];
    const void* g4 = d_in[14];
    const void* b4 = d_in[15];
    hipLaunchKernelGGL(k_wt_final, dim3(1, (FCATC + 31) / 32), dim3(256), 0, stream, W4, flag, Wt);
    hipLaunchKernelGGL((k_gemm<false>), dim3(256 / 64, NPTS / 64), dim3(256), 0, stream,
                       fcat, FCATC, 0, Wt, Y4, FCATC, 256);
    hipLaunchKernelGGL(k_stats_final, dim3(32), dim3(256), 0, stream, Y4, ssum + soff[4], ssq + soff[4]);
    hipLaunchKernelGGL(k_scaleshift, dim3(1), dim3(256), 0, stream,
                       ssum + soff[4], ssq + soff[4], g4, b4, flag,
                       scales + soff[4], shifts + soff[4], 256, 1.f / (float)NPTS);
    hipLaunchKernelGGL(k_feats, dim3(64), dim3(256), 0, stream, Y4, scales + soff[4], shifts + soff[4],
                       d_out, flag, partial);
    hipLaunchKernelGGL(k_gmax, dim3(BATCH), dim3(256), 0, stream, partial, d_out, flag);
}

// Round 5
// 418.964 us; speedup vs baseline: 2.5479x; 1.4163x over previous
//
#include <hip/hip_runtime.h>
#include <hip/hip_bf16.h>

#define BATCH 2
#define NPB   2048
#define NPTS  4096   // BATCH*NPB
#define KNB   27
#define FCATC 1440
#define CSTRIDE 1696   // channel stride for slot partial sums (1440 + 256)
#define NSLOT 32

typedef __hip_bfloat16 bf16;
typedef __attribute__((ext_vector_type(8))) short short8;   // 8 bf16 = 4 VGPRs (MFMA A/B frag)
typedef __attribute__((ext_vector_type(4))) float f32x4;    // MFMA C/D frag

__device__ __forceinline__ float b2f(bf16 v) { return __bfloat162float(v); }

// load input element i from buffer p whose dtype is fp32 (f32=1) or bf16 (f32=0)
__device__ __forceinline__ float ldin(const void* p, size_t i, int f32) {
    return f32 ? ((const float*)p)[i] : b2f(((const bf16*)p)[i]);
}

// ---------------- dtype detect: bf16-interpret x; any huge/NaN => underlying fp32 ----------------
__global__ void k_detect(const void* __restrict__ x, int* __restrict__ flag) {
    __shared__ int s;
    if (threadIdx.x == 0) s = 0;
    __syncthreads();
    const bf16* xb = (const bf16*)x;
    int local = 0;
    for (int i = threadIdx.x; i < NPTS * 3; i += 256) {
        float v = b2f(xb[i]);
        if (!(fabsf(v) < 1e4f)) local = 1;   // catches NaN/Inf/huge
    }
    if (local) s = 1;
    __syncthreads();
    if (threadIdx.x == 0) flag[0] = s;       // 1 => fp32 underlying
}

// ---------------- convert x to fp32 ----------------
__global__ void k_convx(const void* __restrict__ x, const int* __restrict__ flag, float* __restrict__ xf) {
    int i = blockIdx.x * 256 + threadIdx.x;
    if (i >= NPTS * 3) return;
    xf[i] = ldin(x, i, flag[0]);
}

// ---------------- zero accumulators ----------------
__global__ void k_zero(float* p, int n) {
    int i = blockIdx.x * 256 + threadIdx.x;
    if (i < n) p[i] = 0.f;
}

// ---------------- KNN via radix-select: top-27 by max of negative sq dist ----------------
__global__ __launch_bounds__(256) void k_knn(const float* __restrict__ x, int* __restrict__ idx) {
    __shared__ uint hist4[4][260];   // per-wave copies, padded
    __shared__ uint hist[256];
    __shared__ int  tix[NPB];
    __shared__ uint s_phigh;
    __shared__ int  s_rem, s_outcnt, s_tiecnt;

    int bn = blockIdx.x, b = bn >> 11, n = bn & (NPB - 1);
    int tid = threadIdx.x;
    int wv = tid >> 6;
    const float* xb = x + (size_t)b * NPB * 3;
    float cx = xb[n * 3 + 0], cy = xb[n * 3 + 1], cz = xb[n * 3 + 2];
    float cc = cx * cx + cy * cy + cz * cz;

    uint u[8];
    #pragma unroll
    for (int j = 0; j < 8; j++) {
        int m = j * 256 + tid;
        float mx = xb[m * 3 + 0], my = xb[m * 3 + 1], mz = xb[m * 3 + 2];
        float d = 2.f * (cx * mx + cy * my + cz * mz) - cc - (mx * mx + my * my + mz * mz);
        uint s = __float_as_uint(d);
        u[j] = (s & 0x80000000u) ? ~s : (s | 0x80000000u);
    }
    if (tid == 0) { s_phigh = 0; s_rem = KNB; s_outcnt = 0; s_tiecnt = 0; }

    for (int pass = 0; pass < 4; pass++) {
        int shift = 24 - pass * 8;
        hist[tid] = 0;
        for (int i = tid; i < 4 * 260; i += 256) ((uint*)hist4)[i] = 0;
        __syncthreads();
        uint phigh = s_phigh;
        #pragma unroll
        for (int j = 0; j < 8; j++) {
            bool in = (pass == 0) || ((u[j] >> (shift + 8)) == phigh);
            if (in) atomicAdd(&hist4[wv][(u[j] >> shift) & 0xFFu], 1u);
        }
        __syncthreads();
        hist[tid] = hist4[0][tid] + hist4[1][tid] + hist4[2][tid] + hist4[3][tid];
        __syncthreads();
        if (tid < 64) {
            int L = tid;
            uint c0 = hist[L * 4 + 0], c1 = hist[L * 4 + 1], c2 = hist[L * 4 + 2], c3 = hist[L * 4 + 3];
            uint s = c0 + c1 + c2 + c3;
            uint acc = s;
            #pragma unroll
            for (int off = 1; off < 64; off <<= 1) {
                uint t = __shfl_down(acc, off);
                if (L + off < 64) acc += t;
            }
            uint excl = acc - s;
            int rem = s_rem;
            if ((int)excl < rem && (int)acc >= rem) {
                uint cs[4] = { c0, c1, c2, c3 };
                uint cum = excl;
                int bsel = 0; uint hb = 0;
                #pragma unroll
                for (int q = 3; q >= 0; q--) {
                    if ((int)cum < rem && (int)(cum + cs[q]) >= rem && hb == 0u && bsel == 0) {
                        bsel = L * 4 + q; hb = cs[q]; cum += cs[q];
                    } else if (bsel == 0 && hb == 0u) {
                        cum += cs[q];
                    }
                }
                int strictlyAbove = (int)(cum - hb);
                s_rem = rem - strictlyAbove;
                s_phigh = (phigh << 8) | (uint)bsel;
            }
        }
        __syncthreads();
    }

    uint T = s_phigh;
    #pragma unroll
    for (int j = 0; j < 8; j++) {
        int m = j * 256 + tid;
        if (u[j] > T) {
            int p = atomicAdd(&s_outcnt, 1);
            idx[bn * KNB + p] = b * NPB + m;
        } else if (u[j] == T) {
            int p = atomicAdd(&s_tiecnt, 1);
            tix[p] = m;
        }
    }
    __syncthreads();
    int outcnt = s_outcnt, rem = s_rem, tiecnt = s_tiecnt;
    if (tiecnt == rem) {
        if (tid < rem) idx[bn * KNB + outcnt + tid] = b * NPB + tix[tid];
    } else if (tid == 0) {
        for (int t = 0; t < rem; t++) {
            int bi = 0;
            for (int q = 1; q < tiecnt; q++) if (tix[q] < tix[bi]) bi = q;
            idx[bn * KNB + outcnt + t] = b * NPB + tix[bi];
            tix[bi] = 0x7fffffff;
        }
    }
}

// ---------------- layer0 direct: UV[bn][o] (N2=192, Cin=3) ----------------
__global__ void k_l0(const float* __restrict__ xf, const void* __restrict__ W,
                     const int* __restrict__ flag, float* __restrict__ UV) {
    int i = blockIdx.x * 256 + threadIdx.x;
    if (i >= NPTS * 192) return;
    int bn = i / 192, o = i % 192;
    int f32 = flag[0];
    float x0 = xf[bn * 3 + 0], x1 = xf[bn * 3 + 1], x2 = xf[bn * 3 + 2];
    float r;
    if (o < 96) {
        r = x0 * ldin(W, o * 6 + 0, f32) + x1 * ldin(W, o * 6 + 1, f32) + x2 * ldin(W, o * 6 + 2, f32);
    } else {
        int oo = o - 96;
        float w0 = ldin(W, oo * 6 + 3, f32) - ldin(W, oo * 6 + 0, f32);
        float w1 = ldin(W, oo * 6 + 4, f32) - ldin(W, oo * 6 + 1, f32);
        float w2 = ldin(W, oo * 6 + 5, f32) - ldin(W, oo * 6 + 2, f32);
        r = x0 * w0 + x1 * w1 + x2 * w2;
    }
    UV[(size_t)bn * 192 + o] = r;
}

// ---------------- edge weights -> WtT[o][c] bf16 (k-contiguous), u/v transformed ----------------
__global__ void k_wtT(const void* __restrict__ W, const int* __restrict__ flag,
                      bf16* __restrict__ WtT, int Cin, int Co) {
    int o = blockIdx.x;
    int f32 = flag[0];
    if (o < Co) {
        for (int c = threadIdx.x; c < Cin; c += 256)
            WtT[(size_t)o * Cin + c] = __float2bfloat16(ldin(W, (size_t)o * 2 * Cin + c, f32));
    } else {
        int oo = o - Co;
        for (int c = threadIdx.x; c < Cin; c += 256)
            WtT[(size_t)o * Cin + c] = __float2bfloat16(
                ldin(W, (size_t)oo * 2 * Cin + Cin + c, f32) - ldin(W, (size_t)oo * 2 * Cin + c, f32));
    }
}

// ---------------- final weights: W4 is already [o][c] row-major; convert to bf16 ----------------
__global__ void k_wtT4(const void* __restrict__ W4, const int* __restrict__ flag, bf16* __restrict__ WtT) {
    int i = blockIdx.x * 256 + threadIdx.x;
    if (i >= 256 * FCATC) return;
    WtT[i] = __float2bfloat16(ldin(W4, i, flag[0]));
}

// ---------------- MFMA GEMM: C[M x N] = A[M x K] * Bt[N x K]^T, bf16 in, fp32 out ----------------
// 256 threads = 4 waves (2x2), tile 64x64, BK=32. mfma_f32_16x16x32_bf16.
// A frag: A[m=lane&15][k=quad*8+j]; B frag: Bt[n=lane&15][k=quad*8+j]; C/D: col=lane&15,row=quad*4+i.
template <bool ADD>
__global__ __launch_bounds__(256) void k_gemm_mfma(const bf16* __restrict__ A, int lda, int aoff,
                                                   const bf16* __restrict__ Bt, int K,
                                                   float* __restrict__ C, int ldc, int ksz) {
    __shared__ bf16 As[64][40];   // +8 pad: 2-way max bank aliasing
    __shared__ bf16 Bs[64][40];
    int tid = threadIdx.x;
    int wave = tid >> 6, lane = tid & 63;
    int wm = wave >> 1, wn = wave & 1;
    int quad = lane >> 4, l15 = lane & 15;
    int m0 = blockIdx.y * 64, n0 = blockIdx.x * 64;
    int kbase = blockIdx.z * ksz;
    int lr = tid >> 2, lc = (tid & 3) * 8;

    f32x4 acc[2][2] = {};
    for (int k0 = kbase; k0 < kbase + ksz; k0 += 32) {
        *(short8*)&As[lr][lc] = *(const short8*)&A[(size_t)(m0 + lr) * lda + aoff + k0 + lc];
        *(short8*)&Bs[lr][lc] = *(const short8*)&Bt[(size_t)(n0 + lr) * K + k0 + lc];
        __syncthreads();
        short8 af0 = *(const short8*)&As[wm * 32 + l15][quad * 8];
        short8 af1 = *(const short8*)&As[wm * 32 + 16 + l15][quad * 8];
        short8 bf0 = *(const short8*)&Bs[wn * 32 + l15][quad * 8];
        short8 bf1 = *(const short8*)&Bs[wn * 32 + 16 + l15][quad * 8];
        acc[0][0] = __builtin_amdgcn_mfma_f32_16x16x32_bf16(af0, bf0, acc[0][0], 0, 0, 0);
        acc[0][1] = __builtin_amdgcn_mfma_f32_16x16x32_bf16(af0, bf1, acc[0][1], 0, 0, 0);
        acc[1][0] = __builtin_amdgcn_mfma_f32_16x16x32_bf16(af1, bf0, acc[1][0], 0, 0, 0);
        acc[1][1] = __builtin_amdgcn_mfma_f32_16x16x32_bf16(af1, bf1, acc[1][1], 0, 0, 0);
        __syncthreads();
    }
    #pragma unroll
    for (int mt = 0; mt < 2; mt++) {
        #pragma unroll
        for (int nt = 0; nt < 2; nt++) {
            int col = n0 + wn * 32 + nt * 16 + l15;
            #pragma unroll
            for (int i = 0; i < 4; i++) {
                int row = m0 + wm * 32 + mt * 16 + quad * 4 + i;
                float* p = &C[(size_t)row * ldc + col];
                if (ADD) atomicAdd(p, acc[mt][nt][i]);
                else *p = acc[mt][nt][i];
            }
        }
    }
}

// ---------------- fused gather: per point, per channel -> ymax, ymin, sum, sumsq ----------------
__global__ __launch_bounds__(256) void k_gather(float* __restrict__ UV, const int* __restrict__ idx,
                                                bf16* __restrict__ fcat,
                                                float* __restrict__ ssum, float* __restrict__ ssq,
                                                int Co, int out_off) {
    __shared__ int srow[KNB];
    int bn = blockIdx.x;
    int tid = threadIdx.x;
    int N2 = 2 * Co;
    if (tid < KNB) srow[tid] = idx[bn * KNB + tid] * N2;
    __syncthreads();
    int slot = bn & (NSLOT - 1);
    for (int o = tid; o < Co; o += 256) {
        float v = UV[(size_t)bn * N2 + Co + o];
        float ymax = -INFINITY, ymin = INFINITY, s = 0.f, q = 0.f;
        #pragma unroll
        for (int k = 0; k < KNB; k++) {
            float y = UV[(size_t)srow[k] + o] + v;
            ymax = fmaxf(ymax, y);
            ymin = fminf(ymin, y);
            s += y; q += y * y;
        }
        fcat[(size_t)bn * FCATC + out_off + o] = __float2bfloat16(ymax);  // pre-BN max (bf16)
        UV[(size_t)bn * N2 + Co + o] = ymin;                              // stash ymin
        atomicAdd(&ssum[slot * CSTRIDE + o], s);
        atomicAdd(&ssq [slot * CSTRIDE + o], q);
    }
}

// ---------------- scale/shift from 32-slot partials ----------------
__global__ void k_scaleshift(const float* __restrict__ ssum, const float* __restrict__ ssq,
                             const void* __restrict__ g, const void* __restrict__ bb,
                             const int* __restrict__ flag,
                             float* __restrict__ scale, float* __restrict__ shift, int Co, float invcnt) {
    int o = blockIdx.x * 256 + threadIdx.x;
    if (o >= Co) return;
    int f32 = flag[0];
    float s = 0.f, q = 0.f;
    for (int c = 0; c < NSLOT; c++) { s += ssum[c * CSTRIDE + o]; q += ssq[c * CSTRIDE + o]; }
    float mean = s * invcnt;
    float var = q * invcnt - mean * mean;
    float sc = ldin(g, o, f32) * rsqrtf(var + 1e-5f);
    scale[o] = sc;
    shift[o] = ldin(bb, o, f32) - mean * sc;
}

// ---------------- apply BN + lrelu to the pooled value (in place in fcat, bf16) ----------------
__global__ __launch_bounds__(256) void k_apply(const float* __restrict__ UV,
                                               const float* __restrict__ scale, const float* __restrict__ shift,
                                               bf16* __restrict__ fcat, int Co, int out_off) {
    int bn = blockIdx.x;
    int N2 = 2 * Co;
    for (int o = threadIdx.x; o < Co; o += 256) {
        float sc = scale[o], sh = shift[o];
        float y = (sc >= 0.f) ? b2f(fcat[(size_t)bn * FCATC + out_off + o])
                              : UV[(size_t)bn * N2 + Co + o];      // ymin if negative scale
        float z = sc * y + sh;
        z = (z >= 0.f) ? z : 0.2f * z;
        fcat[(size_t)bn * FCATC + out_off + o] = __float2bfloat16(z);
    }
}

// ---------------- final BN stats over (B,N): direct per-slot writes ----------------
__global__ void k_stats_final(const float* __restrict__ Y, float* __restrict__ ssum, float* __restrict__ ssq) {
    int o = threadIdx.x;
    int p0 = blockIdx.x * 128;
    float s = 0, q = 0;
    for (int p = 0; p < 128; p++) {
        float y = Y[(size_t)(p0 + p) * 256 + o];
        s += y; q += y * y;
    }
    ssum[blockIdx.x * CSTRIDE + o] = s;
    ssq [blockIdx.x * CSTRIDE + o] = q;
}

// ---------------- feats (dtype per flag) + per-chunk max ----------------
__global__ void k_feats(const float* __restrict__ Y, const float* __restrict__ scale, const float* __restrict__ shift,
                        void* __restrict__ out, const int* __restrict__ flag, float* __restrict__ partial) {
    int o = threadIdx.x;
    int chunk = blockIdx.x;
    int bn0 = chunk * 64;
    int f32 = flag[0];
    float sc = scale[o], sh = shift[o];
    float best = -INFINITY;
    for (int i = 0; i < 64; i++) {
        int bn = bn0 + i;
        float z = sc * Y[(size_t)bn * 256 + o] + sh;
        z = (z >= 0.f) ? z : 0.2f * z;
        size_t oi = (size_t)BATCH * 256 + (size_t)bn * 256 + o;
        if (f32) ((float*)out)[oi] = z;
        else     ((bf16*)out)[oi] = __float2bfloat16(z);
        best = fmaxf(best, z);
    }
    partial[chunk * 256 + o] = best;
}

__global__ void k_gmax(const float* __restrict__ partial, void* __restrict__ out, const int* __restrict__ flag) {
    int o = threadIdx.x;
    int b = blockIdx.x;
    float best = -INFINITY;
    for (int c = 0; c < 32; c++) best = fmaxf(best, partial[(b * 32 + c) * 256 + o]);
    if (flag[0]) ((float*)out)[b * 256 + o] = best;
    else         ((bf16*)out)[b * 256 + o] = __float2bfloat16(best);
}

// ---------------- launch ----------------
extern "C" void kernel_launch(void* const* d_in, const int* in_sizes, int n_in,
                              void* d_out, int out_size, void* d_ws, size_t ws_size,
                              hipStream_t stream) {
    const void* x = d_in[0];

    char* ws = (char*)d_ws;
    int*   idx    = (int*)  (ws + 0);                 // 4096*27 int
    float* UV     = (float*)(ws + 442368);            // 4096 x 1536 f32
    bf16*  fcat   = (bf16*) (ws + 25608192);          // 4096 x 1440 bf16 (11.8 MB)
    float* Y4     = (float*)(ws + 49201152);          // 4096 x 256 f32
    bf16*  WtT    = (bf16*) (ws + 53395456);          // max 1536x384 bf16 (1.18 MB); reused for W4T
    float* slots  = (float*)(ws + 55795456);          // 2 x 32 x 1696 f32
    float* ssum   = slots;
    float* ssq    = slots + NSLOT * CSTRIDE;
    float* scales = (float*)(ws + 58114048);          // 1696
    float* shifts = scales + 1696;
    float* partial= (float*)(ws + 58141184);          // 64 x 256
    float* xf     = (float*)(ws + 58206720);          // 12288 f32
    int*   flag   = (int*)  (ws + 58255872);          // 1

    const int Cin[4]  = {3, 96, 192, 384};
    const int Co[4]   = {96, 192, 384, 768};
    const int ooff[4] = {0, 96, 288, 672};
    const int soff[5] = {0, 96, 288, 672, 1440};

    hipLaunchKernelGGL(k_detect, dim3(1), dim3(256), 0, stream, x, flag);
    hipLaunchKernelGGL(k_convx, dim3(48), dim3(256), 0, stream, x, flag, xf);
    hipLaunchKernelGGL(k_zero, dim3((2 * NSLOT * CSTRIDE + 255) / 256), dim3(256), 0, stream,
                       slots, 2 * NSLOT * CSTRIDE);
    hipLaunchKernelGGL(k_zero, dim3((NPTS * 256 + 255) / 256), dim3(256), 0, stream,
                       Y4, NPTS * 256);
    hipLaunchKernelGGL(k_knn, dim3(NPTS), dim3(256), 0, stream, xf, idx);

    const float invcnt_edge = 1.f / (float)(NPTS * KNB);
    for (int L = 0; L < 4; L++) {
        const void* W  = d_in[1 + 3 * L];
        const void* g  = d_in[2 + 3 * L];
        const void* bb = d_in[3 + 3 * L];
        int N2 = 2 * Co[L];
        if (L == 0) {
            hipLaunchKernelGGL(k_l0, dim3((NPTS * 192 + 255) / 256), dim3(256), 0, stream,
                               xf, W, flag, UV);
        } else {
            hipLaunchKernelGGL(k_wtT, dim3(N2), dim3(256), 0, stream, W, flag, WtT, Cin[L], Co[L]);
            hipLaunchKernelGGL((k_gemm_mfma<false>), dim3(N2 / 64, NPTS / 64, 1), dim3(256), 0, stream,
                               fcat, FCATC, ooff[L - 1], WtT, Cin[L], UV, N2, Cin[L]);
        }
        hipLaunchKernelGGL(k_gather, dim3(NPTS), dim3(256), 0, stream,
                           UV, idx, fcat, ssum + soff[L], ssq + soff[L], Co[L], ooff[L]);
        hipLaunchKernelGGL(k_scaleshift, dim3((Co[L] + 255) / 256), dim3(256), 0, stream,
                           ssum + soff[L], ssq + soff[L], g, bb, flag,
                           scales + soff[L], shifts + soff[L], Co[L], invcnt_edge);
        hipLaunchKernelGGL(k_apply, dim3(NPTS), dim3(256), 0, stream,
                           UV, scales + soff[L], shifts + soff[L], fcat, Co[L], ooff[L]);
    }

    // final 1440 -> 256 (split-K x5, 288 each, atomic accumulate into zeroed Y4)
    const void* W4 = d_in[13];
    const void* g4 = d_in[14];
    const void* b4 = d_in[15];
    hipLaunchKernelGGL(k_wtT4, dim3((256 * FCATC + 255) / 256), dim3(256), 0, stream, W4, flag, WtT);
    hipLaunchKernelGGL((k_gemm_mfma<true>), dim3(256 / 64, NPTS / 64, 5), dim3(256), 0, stream,
                       fcat, FCATC, 0, WtT, FCATC, Y4, 256, 288);
    hipLaunchKernelGGL(k_stats_final, dim3(32), dim3(256), 0, stream, Y4, ssum + soff[4], ssq + soff[4]);
    hipLaunchKernelGGL(k_scaleshift, dim3(1), dim3(256), 0, stream,
                       ssum + soff[4], ssq + soff[4], g4, b4, flag,
                       scales + soff[4], shifts + soff[4], 256, 1.f / (float)NPTS);
    hipLaunchKernelGGL(k_feats, dim3(64), dim3(256), 0, stream, Y4, scales + soff[4], shifts + soff[4],
                       d_out, flag, partial);
    hipLaunchKernelGGL(k_gmax, dim3(BATCH), dim3(256), 0, stream, partial, d_out, flag);
}